// Round 9
// baseline (272.548 us; speedup 1.0000x reference)
//
#include <hip/hip_runtime.h>
#include <math.h>

#define BB 1024        // batch
#define DD 512         // feature dim
#define CC 50000       // classes
#define KMAX 1024      // max compacted classes
#define HSZ 2048       // hash size
#define PLCAP 64       // per-row positive-list capacity (expected ~2)
#define NB 512         // persistent grid: 2 blocks/CU guaranteed co-resident
#define SCALE_F 16.0f
#define EPS_F 0.1f

typedef __bf16 bf16_t;
typedef bf16_t bf16x8 __attribute__((ext_vector_type(8)));
typedef float f32x4 __attribute__((ext_vector_type(4)));

__device__ __forceinline__ unsigned hashc(int c) {
    return ((unsigned)c * 2654435761u) >> 21;   // 0..2047
}

__device__ __forceinline__ void hash_insert(int* gkey, int* gval, int* kctr,
                                            int* sc, int c) {
    unsigned h = hashc(c);
    while (true) {
        int old = atomicCAS(&gkey[h], -1, c);
        if (old == -1) {                  // owner: allocate rank
            int r = atomicAdd(kctr, 1);
            gval[h] = r;
            if (r < KMAX) sc[r] = c;
            break;
        }
        if (old == c) break;
        h = (h + 1) & (HSZ - 1);
    }
}

// grid-wide barrier: arrive counter + flag spin; agent-scope atomics handle
// cross-XCD visibility (L2 writeback on release, invalidate on acquire).
// Deadlock-safe: NB=512 <= guaranteed co-resident capacity (see launch_bounds).
__device__ __forceinline__ void gsync(int* ctr, int* flag, int idx) {
    __syncthreads();
    if (threadIdx.x == 0) {
        __threadfence();
        int arrived = __hip_atomic_fetch_add(&ctr[idx], 1, __ATOMIC_ACQ_REL,
                                             __HIP_MEMORY_SCOPE_AGENT);
        if (arrived == NB - 1) {
            __hip_atomic_store(&flag[idx], 1, __ATOMIC_RELEASE,
                               __HIP_MEMORY_SCOPE_AGENT);
        } else {
            while (__hip_atomic_load(&flag[idx], __ATOMIC_ACQUIRE,
                                     __HIP_MEMORY_SCOPE_AGENT) == 0)
                __builtin_amdgcn_s_sleep(8);
        }
    }
    __syncthreads();
}

// pm streaming scan of one full row: emit (rank, value) for nonzeros at valid
// classes. hash lives in LDS (hk/hv).
__device__ __forceinline__ void scan_row(const float* __restrict__ pm, int b,
                                         const int* hk, const int* hv,
                                         int* pcnt, int* pkidx, float* pval) {
    const f32x4* __restrict__ rowv = (const f32x4*)(pm + (size_t)b * CC);
    for (int i = threadIdx.x; i < CC / 4; i += 256) {
        f32x4 v = rowv[i];
        if (v[0] != 0.0f || v[1] != 0.0f || v[2] != 0.0f || v[3] != 0.0f) {
            #pragma unroll
            for (int j = 0; j < 4; ++j) {
                if (v[j] != 0.0f) {
                    int c = i * 4 + j;
                    unsigned h = hashc(c);
                    while (true) {
                        int k = hk[h];
                        if (k == c) {
                            int r = hv[h];
                            if (r < KMAX) {
                                int slot = atomicAdd(&pcnt[b], 1);
                                if (slot < PLCAP) {
                                    pkidx[b * PLCAP + slot] = r;
                                    pval[b * PLCAP + slot] = v[j];
                                }
                            }
                            break;
                        }
                        if (k == -1) break;   // not a valid class
                        h = (h + 1) & (HSZ - 1);
                    }
                }
            }
        }
    }
}

// 32x32 MFMA tile (bf16 3-term split on raw values, fp32 accum); epilogue
// scales by 16*rnA*rnB, stores simc, accumulates seAcc[row] += sum exp(sim).
__device__ __forceinline__ void gemm_tile(int t, int Kv,
        const bf16_t* __restrict__ AH, const bf16_t* __restrict__ AL,
        const bf16_t* __restrict__ BH, const bf16_t* __restrict__ BL,
        const float* __restrict__ rnA, const float* __restrict__ rnB,
        float* __restrict__ simc, float* __restrict__ seAcc, float* sem) {
    int tid = threadIdx.x;
    if (tid < 32) sem[tid] = 0.0f;
    __syncthreads();
    int wave = tid >> 6, lane = tid & 63;
    int by = t >> 5, bx = t & 31;
    int b0 = by * 32 + (wave >> 1) * 16;
    int k0 = bx * 32 + (wave & 1) * 16;
    int frow = lane & 15;
    int koff = (lane >> 4) * 8;
    const bf16_t* pAh = AH + (size_t)(b0 + frow) * DD + koff;
    const bf16_t* pAl = AL + (size_t)(b0 + frow) * DD + koff;
    const bf16_t* pBh = BH + (size_t)(k0 + frow) * DD + koff;
    const bf16_t* pBl = BL + (size_t)(k0 + frow) * DD + koff;
    f32x4 acc = {};
    #pragma unroll 2
    for (int dk = 0; dk < DD; dk += 32) {
        bf16x8 ah = *(const bf16x8*)(pAh + dk);
        bf16x8 al = *(const bf16x8*)(pAl + dk);
        bf16x8 bh = *(const bf16x8*)(pBh + dk);
        bf16x8 bl = *(const bf16x8*)(pBl + dk);
        acc = __builtin_amdgcn_mfma_f32_16x16x32_bf16(ah, bh, acc, 0, 0, 0);
        acc = __builtin_amdgcn_mfma_f32_16x16x32_bf16(ah, bl, acc, 0, 0, 0);
        acc = __builtin_amdgcn_mfma_f32_16x16x32_bf16(al, bh, acc, 0, 0, 0);
    }
    // C/D layout: col = lane&15, row = (lane>>4)*4 + reg
    int r4 = (lane >> 4) * 4;
    int col = k0 + (lane & 15);
    float rb = rnB[col];
    #pragma unroll
    for (int r = 0; r < 4; ++r) {
        int row = b0 + r4 + r;
        float s = acc[r] * SCALE_F * rnA[row] * rb;
        simc[(size_t)row * KMAX + col] = s;
        float e = (col < Kv) ? expf(s) : 0.0f;
        #pragma unroll
        for (int o = 1; o < 16; o <<= 1) e += __shfl_xor(e, o, 16);
        if ((lane & 15) == 0) atomicAdd(&sem[(wave >> 1) * 16 + r4 + r], e);
    }
    __syncthreads();
    if (tid < 32) atomicAdd(&seAcc[by * 32 + tid], sem[tid]);
    __syncthreads();
}

__global__ __launch_bounds__(256, 2) void k_fused(
        const float* __restrict__ inputs, const float* __restrict__ pm,
        const float* __restrict__ fmem, const int* __restrict__ lmem,
        const int* __restrict__ targets,
        int* gkey, int* gval, int* sc, int* rowrank, int* kctr,
        int* pcnt, int* pkidx, float* pval, float* seAcc,
        float* rnA, float* rnB,
        bf16_t* AH, bf16_t* AL, bf16_t* BH, bf16_t* BL,
        float* simc, int* ctr, int* flag, float* outp) {
    __shared__ int hk[HSZ];
    __shared__ int hv[HSZ];
    __shared__ int members[BB];
    __shared__ float red[256];
    __shared__ float sem[32];
    __shared__ int mcount;
    int bid = blockIdx.x, tid = threadIdx.x;

    // ---------------- P1: hash inserts (targets + lmem) ----------------
    if (bid < 4) {
        hash_insert(gkey, gval, kctr, sc, targets[bid * 256 + tid]);
    } else if (bid < 200) {
        int c = (bid - 4) * 256 + tid;
        if (c < CC && lmem[c] != -1) hash_insert(gkey, gval, kctr, sc, c);
    }
    gsync(ctr, flag, 0);

    // ---------------- P2: hash->LDS; splits + class sums + rowrank -----
    for (int i = tid; i < HSZ; i += 256) { hk[i] = gkey[i]; hv[i] = gval[i]; }
    __syncthreads();
    int Kv = *kctr; if (Kv > KMAX) Kv = KMAX;
    int d0 = tid * 2;
    for (int j = 0; j < 2; ++j) {
        int b = bid + j * NB;
        // row split + rnA + rowrank
        float a0 = inputs[b * DD + d0];
        float a1 = inputs[b * DD + d0 + 1];
        red[tid] = a0 * a0 + a1 * a1;
        __syncthreads();
        for (int s = 128; s > 0; s >>= 1) {
            if (tid < s) red[tid] += red[tid + s];
            __syncthreads();
        }
        if (tid == 0) {
            rnA[b] = 1.0f / fmaxf(sqrtf(red[0]), 1e-12f);
            int c = targets[b];
            unsigned h = hashc(c);
            while (hk[h] != c) h = (h + 1) & (HSZ - 1);
            rowrank[b] = hv[h];
        }
        bf16_t h0 = (bf16_t)a0, h1 = (bf16_t)a1;
        AH[b * DD + d0] = h0; AH[b * DD + d0 + 1] = h1;
        AL[b * DD + d0] = (bf16_t)(a0 - (float)h0);
        AL[b * DD + d0 + 1] = (bf16_t)(a1 - (float)h1);
        __syncthreads();
        // class sum k = b (block-uniform branch)
        int k = b;
        if (k < Kv) {
            int c = sc[k];
            if (tid == 0) mcount = 0;
            __syncthreads();
            int4 t4 = *(const int4*)(targets + tid * 4);
            if (t4.x == c) { int s = atomicAdd(&mcount, 1); members[s] = tid * 4 + 0; }
            if (t4.y == c) { int s = atomicAdd(&mcount, 1); members[s] = tid * 4 + 1; }
            if (t4.z == c) { int s = atomicAdd(&mcount, 1); members[s] = tid * 4 + 2; }
            if (t4.w == c) { int s = atomicAdd(&mcount, 1); members[s] = tid * 4 + 3; }
            __syncthreads();
            int mc = mcount;
            float b0v = 0.0f, b1v = 0.0f;
            if (mc == 0) {                 // lmem-only class: memory row
                b0v = fmem[(size_t)c * DD + d0];
                b1v = fmem[(size_t)c * DD + d0 + 1];
            } else {                       // sum member rows (/count cancels)
                for (int i = 0; i < mc; ++i) {
                    int bb = members[i];
                    b0v += inputs[bb * DD + d0];
                    b1v += inputs[bb * DD + d0 + 1];
                }
            }
            red[tid] = b0v * b0v + b1v * b1v;
            __syncthreads();
            for (int s = 128; s > 0; s >>= 1) {
                if (tid < s) red[tid] += red[tid + s];
                __syncthreads();
            }
            if (tid == 0) rnB[k] = 1.0f / fmaxf(sqrtf(red[0]), 1e-12f);
            bf16_t g0 = (bf16_t)b0v, g1 = (bf16_t)b1v;
            BH[k * DD + d0] = g0; BH[k * DD + d0 + 1] = g1;
            BL[k * DD + d0] = (bf16_t)(b0v - (float)g0);
            BL[k * DD + d0 + 1] = (bf16_t)(b1v - (float)g1);
            __syncthreads();
        } else {                           // zero-pad so GEMM reads zeros
            BH[k * DD + d0] = (bf16_t)0.0f; BH[k * DD + d0 + 1] = (bf16_t)0.0f;
            BL[k * DD + d0] = (bf16_t)0.0f; BL[k * DD + d0 + 1] = (bf16_t)0.0f;
            if (tid == 0) rnB[k] = 0.0f;
            __syncthreads();
        }
    }
    gsync(ctr, flag, 1);

    // ---------------- P3: pm scan (2 rows) ∥ GEMM (2 tiles), staggered --
    if (bid & 1) {
        gemm_tile(bid, Kv, AH, AL, BH, BL, rnA, rnB, simc, seAcc, sem);
        gemm_tile(bid + NB, Kv, AH, AL, BH, BL, rnA, rnB, simc, seAcc, sem);
        scan_row(pm, bid, hk, hv, pcnt, pkidx, pval);
        scan_row(pm, bid + NB, hk, hv, pcnt, pkidx, pval);
    } else {
        scan_row(pm, bid, hk, hv, pcnt, pkidx, pval);
        scan_row(pm, bid + NB, hk, hv, pcnt, pkidx, pval);
        gemm_tile(bid, Kv, AH, AL, BH, BL, rnA, rnB, simc, seAcc, sem);
        gemm_tile(bid + NB, Kv, AH, AL, BH, BL, rnA, rnB, simc, seAcc, sem);
    }
    gsync(ctr, flag, 2);

    // ---------------- P4: loss tail (block 0 only) ----------------------
    if (bid != 0) return;
    float accl = 0.0f;
    for (int j = 0; j < 4; ++j) {
        int b = tid + j * 256;
        float seb = seAcc[b];
        int cnt = pcnt[b]; if (cnt > PLCAP) cnt = PLCAP;
        int rt = rowrank[b];
        const float* __restrict__ srow = simc + (size_t)b * KMAX;
        float st = srow[rt];
        float sp = 0.0f, spe = 0.0f;
        for (int i = 0; i < cnt; ++i) {
            float v = pval[b * PLCAP + i];
            sp += v;
            spe += v * expf(srow[pkidx[b * PLCAP + i]]);
        }
        float sneg = seb - spe;            // sum (1-pm)*exp over valid
        float lb = (1.0f - EPS_F) * (st - logf(sneg + expf(st)));
        float inv = EPS_F / sp;
        for (int i = 0; i < cnt; ++i) {
            float s = srow[pkidx[b * PLCAP + i]];
            lb += inv * pval[b * PLCAP + i] * (s - logf(sneg + expf(s)));
        }
        accl += lb;
    }
    red[tid] = accl;
    __syncthreads();
    for (int s = 128; s > 0; s >>= 1) {
        if (tid < s) red[tid] += red[tid + s];
        __syncthreads();
    }
    if (tid == 0) outp[0] = -red[0] * (1.0f / BB);
}

extern "C" void kernel_launch(void* const* d_in, const int* in_sizes, int n_in,
                              void* d_out, int out_size, void* d_ws, size_t ws_size,
                              hipStream_t stream) {
    const float* inputs  = (const float*)d_in[0];
    const float* pmask   = (const float*)d_in[1];
    const float* fmem    = (const float*)d_in[2];
    const int*   lmem    = (const int*)d_in[3];
    const int*   targets = (const int*)d_in[4];
    float* outp = (float*)d_out;

    char* ws = (char*)d_ws;
    size_t off = 0;
    auto alloc = [&](size_t bytes) -> void* {
        void* p = ws + off;
        off = (off + bytes + 255) & ~(size_t)255;
        return p;
    };
    // hash block: one memset 0xFF over gkey+gval (contiguous, 256-mult sizes)
    int*    gkey    = (int*)alloc(HSZ * sizeof(int));   // 8192
    int*    gval    = (int*)alloc(HSZ * sizeof(int));   // 8192
    // zero block: pcnt + seAcc + misc (contiguous)
    int*    pcnt    = (int*)alloc(BB * sizeof(int));    // 4096
    float*  seAcc   = (float*)alloc(BB * sizeof(float));// 4096
    int*    misc    = (int*)alloc(256);                 // kctr/ctr/flag
    int*    kctr    = misc;
    int*    ctr     = misc + 8;
    int*    flag    = misc + 16;
    int*    sc      = (int*)alloc(KMAX * sizeof(int));
    int*    rowrank = (int*)alloc(BB * sizeof(int));
    int*    pkidx   = (int*)alloc((size_t)BB * PLCAP * sizeof(int));
    float*  pval    = (float*)alloc((size_t)BB * PLCAP * sizeof(float));
    float*  rnA     = (float*)alloc(BB * sizeof(float));
    float*  rnB     = (float*)alloc(KMAX * sizeof(float));
    bf16_t* AH      = (bf16_t*)alloc((size_t)BB * DD * sizeof(bf16_t));
    bf16_t* AL      = (bf16_t*)alloc((size_t)BB * DD * sizeof(bf16_t));
    bf16_t* BH      = (bf16_t*)alloc((size_t)KMAX * DD * sizeof(bf16_t));
    bf16_t* BL      = (bf16_t*)alloc((size_t)KMAX * DD * sizeof(bf16_t));
    float*  simc    = (float*)alloc((size_t)BB * KMAX * sizeof(float));

    hipMemsetAsync(gkey, 0xFF, 2 * HSZ * sizeof(int), stream);        // keys = -1
    hipMemsetAsync(pcnt, 0, BB * sizeof(int) + BB * sizeof(float) + 256, stream);

    k_fused<<<NB, 256, 0, stream>>>(inputs, pmask, fmem, lmem, targets,
                                    gkey, gval, sc, rowrank, kctr,
                                    pcnt, pkidx, pval, seAcc, rnA, rnB,
                                    AH, AL, BH, BL, simc, ctr, flag, outp);
}